// Round 2
// baseline (515.276 us; speedup 1.0000x reference)
//
#include <hip/hip_runtime.h>
#include <math.h>

#define NJ 24

// SMPL-style kinematic tree; parent index always < child index.
__device__ __constant__ int c_parents[NJ] = {
    -1, 0, 0, 0, 1, 2, 3, 4, 5, 6, 7, 8, 9, 9, 9, 12, 13, 14, 16, 17, 18, 19, 20, 21};

__device__ inline void mat4mul(const float* A, const float* B, float* C) {
#pragma unroll
    for (int r = 0; r < 4; ++r) {
#pragma unroll
        for (int c = 0; c < 4; ++c) {
            C[r * 4 + c] = A[r * 4 + 0] * B[0 * 4 + c] + A[r * 4 + 1] * B[1 * 4 + c] +
                           A[r * 4 + 2] * B[2 * 4 + c] + A[r * 4 + 3] * B[3 * 4 + c];
        }
    }
}

// One block per batch element. Threads 0..23 build local joint transforms,
// thread 0 walks the (tiny, serial) kinematic chain, threads 0..23 compose
// with init_pose and write out. Also computes trans + extra_trans.
__global__ __launch_bounds__(64) void build_A_kernel(
    const float* __restrict__ poses,      // [B, NJ, 3]
    const float* __restrict__ trans,      // [B, 3]
    const float* __restrict__ Js,         // [NJ, 3]
    const float* __restrict__ init_pose,  // [NJ, 4, 4]
    const float* __restrict__ extra_trans,// [1, 3]
    float* __restrict__ A_out,            // [B, NJ, 16]
    float* __restrict__ trans_out,        // [B, 3]
    int B)
{
    __shared__ float Aloc[NJ][16];  // local transforms, composed in place
    int b = blockIdx.x;
    int j = threadIdx.x;

    if (j < NJ) {
        float rx = poses[((size_t)b * NJ + j) * 3 + 0];
        float ry = poses[((size_t)b * NJ + j) * 3 + 1];
        float rz = poses[((size_t)b * NJ + j) * 3 + 2];
        float dot = rx * rx + ry * ry + rz * rz + 1e-12f;
        float angle = sqrtf(dot);
        float inv = 1.0f / angle;
        float ax = rx * inv, ay = ry * inv, az = rz * inv;
        float s = sinf(angle), c = cosf(angle);
        float ic = 1.0f - c;
        // R = c*I + s*K + (1-c)*a a^T  (Rodrigues)
        float R00 = c + ic * ax * ax;
        float R01 = ic * ax * ay - s * az;
        float R02 = ic * ax * az + s * ay;
        float R10 = ic * ax * ay + s * az;
        float R11 = c + ic * ay * ay;
        float R12 = ic * ay * az - s * ax;
        float R20 = ic * ax * az - s * ay;
        float R21 = ic * ay * az + s * ax;
        float R22 = c + ic * az * az;

        int p = c_parents[j];
        float tx = Js[j * 3 + 0], ty = Js[j * 3 + 1], tz = Js[j * 3 + 2];
        if (p >= 0) {
            tx -= Js[p * 3 + 0];
            ty -= Js[p * 3 + 1];
            tz -= Js[p * 3 + 2];
        }
        Aloc[j][0] = R00; Aloc[j][1] = R01; Aloc[j][2]  = R02; Aloc[j][3]  = tx;
        Aloc[j][4] = R10; Aloc[j][5] = R11; Aloc[j][6]  = R12; Aloc[j][7]  = ty;
        Aloc[j][8] = R20; Aloc[j][9] = R21; Aloc[j][10] = R22; Aloc[j][11] = tz;
        Aloc[j][12] = 0.f; Aloc[j][13] = 0.f; Aloc[j][14] = 0.f; Aloc[j][15] = 1.f;
    }
    __syncthreads();

    if (j == 0) {
        // serial chain composition; parents always precede children
        for (int i = 1; i < NJ; ++i) {
            int p = c_parents[i];
            float tmp[16];
            mat4mul(Aloc[p], Aloc[i], tmp);
#pragma unroll
            for (int k = 0; k < 16; ++k) Aloc[i][k] = tmp[k];
        }
    }
    __syncthreads();

    if (j < NJ) {
        float outm[16];
        float ip[16];
#pragma unroll
        for (int k = 0; k < 16; ++k) ip[k] = init_pose[j * 16 + k];
        mat4mul(Aloc[j], ip, outm);
#pragma unroll
        for (int k = 0; k < 16; ++k) A_out[((size_t)b * NJ + j) * 16 + k] = outm[k];
    }
    if (j < 3) {
        trans_out[b * 3 + j] = trans[b * 3 + j] + extra_trans[j];
    }
}

// Transpose [NJ, NVOX] (channel-first) -> [NVOX, NJ] (channel-last).
// Each thread handles 4 consecutive voxels: reads are fully coalesced
// (float4 per channel), writes cover a contiguous 384B chunk per thread.
__global__ __launch_bounds__(256) void transpose_kernel(
    const float* __restrict__ src, float* __restrict__ dst, size_t NVOX)
{
    size_t t = (size_t)blockIdx.x * 256 + threadIdx.x;
    size_t stride = (size_t)gridDim.x * 256 * 4;
    for (size_t v0 = t * 4; v0 < NVOX; v0 += stride) {
        if (v0 + 4 <= NVOX) {
            float4 q[NJ];
#pragma unroll
            for (int c = 0; c < NJ; ++c)
                q[c] = *(const float4*)(src + (size_t)c * NVOX + v0);
#pragma unroll
            for (int k = 0; k < 4; ++k) {
                float* o = dst + (v0 + k) * NJ;
                const float* qf = (const float*)q;
#pragma unroll
                for (int c4 = 0; c4 < NJ; c4 += 4) {
                    float4 w4;
                    w4.x = qf[(c4 + 0) * 4 + k];
                    w4.y = qf[(c4 + 1) * 4 + k];
                    w4.z = qf[(c4 + 2) * 4 + k];
                    w4.w = qf[(c4 + 3) * 4 + k];
                    *(float4*)(o + c4) = w4;
                }
            }
        } else {
            for (size_t v = v0; v < NVOX; ++v)
                for (int c = 0; c < NJ; ++c)
                    dst[v * NJ + c] = src[(size_t)c * NVOX + v];
        }
    }
}

// Main fused kernel: trilinear sample of 24 skinning weights + blend of the
// 24 joint transforms + point transform. CHL=true reads the channel-last
// transposed volume (fast path); CHL=false reads the original layout.
template <bool CHL>
__global__ __launch_bounds__(256) void skin_kernel(
    const float* __restrict__ ps,     // [B, N, 3]
    const float* __restrict__ vol,    // CHL ? [NVOX, NJ] : [NJ, NVOX]
    const float* __restrict__ A,      // [B, NJ, 16]
    const float* __restrict__ transT, // [B, 3]
    const float* __restrict__ bext,   // [3]
    const float* __restrict__ bcen,   // [3]
    float* __restrict__ out,          // [B, N, 3]
    int N, int G)
{
    __shared__ __align__(16) float As[NJ * 16];
    __shared__ float trs[3];
    int b = blockIdx.y;
    int t = threadIdx.x;
    for (int k = t; k < NJ * 16; k += 256) As[k] = A[(size_t)b * NJ * 16 + k];
    if (t < 3) trs[t] = transT[b * 3 + t];
    __syncthreads();

    int i = blockIdx.x * 256 + t;
    if (i >= N) return;

    size_t pix = ((size_t)b * N + i) * 3;
    float px = ps[pix + 0];
    float py = ps[pix + 1];
    float pz = ps[pix + 2];

    float nx = (px - bcen[0]) / bext[0] * 2.0f;
    float ny = (py - bcen[1]) / bext[1] * 2.0f;
    float nz = (pz - bcen[2]) / bext[2] * 2.0f;

    float fG = (float)G;
    float ixf = (nx + 1.0f) * 0.5f * fG - 0.5f;
    float iyf = (ny + 1.0f) * 0.5f * fG - 0.5f;
    float izf = (nz + 1.0f) * 0.5f * fG - 0.5f;

    int x0 = (int)floorf(ixf);
    int y0 = (int)floorf(iyf);
    int z0 = (int)floorf(izf);
    float fx = ixf - (float)x0;
    float fy = iyf - (float)y0;
    float fz = izf - (float)z0;

    float w[NJ];
#pragma unroll
    for (int j = 0; j < NJ; ++j) w[j] = 0.0f;

    const size_t NVOX = (size_t)G * G * G;

#pragma unroll
    for (int cz = 0; cz < 2; ++cz) {
#pragma unroll
        for (int cy = 0; cy < 2; ++cy) {
#pragma unroll
            for (int cx = 0; cx < 2; ++cx) {
                int X = x0 + cx, Y = y0 + cy, Z = z0 + cz;
                float cw = (cx ? fx : 1.0f - fx) * (cy ? fy : 1.0f - fy) *
                           (cz ? fz : 1.0f - fz);
                if (X >= 0 && X < G && Y >= 0 && Y < G && Z >= 0 && Z < G) {
                    size_t vidx = ((size_t)Z * G + Y) * (size_t)G + X;
                    if (CHL) {
                        const float4* q4 = (const float4*)(vol + vidx * NJ);
#pragma unroll
                        for (int k = 0; k < 6; ++k) {
                            float4 v4 = q4[k];
                            w[4 * k + 0] += cw * v4.x;
                            w[4 * k + 1] += cw * v4.y;
                            w[4 * k + 2] += cw * v4.z;
                            w[4 * k + 3] += cw * v4.w;
                        }
                    } else {
#pragma unroll
                        for (int j = 0; j < NJ; ++j)
                            w[j] += cw * vol[(size_t)j * NVOX + vidx];
                    }
                }
            }
        }
    }

    // T = sum_j w[j] * A[b,j]  (rows 0..2 only), then v = T[:3,:3] p + T[:3,3]
    float o[3];
#pragma unroll
    for (int r = 0; r < 3; ++r) {
        float t0 = 0.f, t1 = 0.f, t2 = 0.f, t3 = 0.f;
#pragma unroll
        for (int j = 0; j < NJ; ++j) {
            float4 a4 = *(const float4*)&As[j * 16 + r * 4];
            t0 += w[j] * a4.x;
            t1 += w[j] * a4.y;
            t2 += w[j] * a4.z;
            t3 += w[j] * a4.w;
        }
        o[r] = t0 * px + t1 * py + t2 * pz + t3 + trs[r];
    }

    out[pix + 0] = o[0];
    out[pix + 1] = o[1];
    out[pix + 2] = o[2];
}

extern "C" void kernel_launch(void* const* d_in, const int* in_sizes, int n_in,
                              void* d_out, int out_size, void* d_ws, size_t ws_size,
                              hipStream_t stream) {
    const float* ps        = (const float*)d_in[0];
    const float* poses     = (const float*)d_in[1];
    const float* trans     = (const float*)d_in[2];
    const float* ws        = (const float*)d_in[3];
    const float* Js        = (const float*)d_in[4];
    const float* init_pose = (const float*)d_in[5];
    const float* bext      = (const float*)d_in[6];
    const float* bcen      = (const float*)d_in[7];
    const float* etr       = (const float*)d_in[8];
    float* out = (float*)d_out;

    int B = in_sizes[2] / 3;
    int N = in_sizes[0] / (3 * B);
    long long wsz = in_sizes[3];
    int G = (int)(cbrt((double)(wsz / NJ)) + 0.5);
    size_t NVOX = (size_t)G * G * G;

    // Workspace layout (floats): [A: B*NJ*16][trans: B*3][pad][vol_t: NVOX*NJ]
    size_t a_floats = (size_t)B * NJ * 16;
    size_t t_floats = (size_t)B * 3;
    size_t vol_off = (a_floats + t_floats + 63) & ~(size_t)63;  // 256B align
    size_t need_bytes = (vol_off + NVOX * NJ) * sizeof(float);

    float* A_buf = (float*)d_ws;
    float* tr_buf = A_buf + a_floats;
    float* vol_t = (float*)d_ws + vol_off;

    bool use_transposed = (ws_size >= need_bytes);

    build_A_kernel<<<B, 64, 0, stream>>>(poses, trans, Js, init_pose, etr,
                                         A_buf, tr_buf, B);

    dim3 grid((unsigned)((N + 255) / 256), (unsigned)B);
    if (use_transposed) {
        int nb = (int)((NVOX / 4 + 255) / 256);
        transpose_kernel<<<nb, 256, 0, stream>>>(ws, vol_t, NVOX);
        skin_kernel<true><<<grid, 256, 0, stream>>>(ps, vol_t, A_buf, tr_buf,
                                                    bext, bcen, out, N, G);
    } else {
        skin_kernel<false><<<grid, 256, 0, stream>>>(ps, ws, A_buf, tr_buf,
                                                     bext, bcen, out, N, G);
    }
}

// Round 3
// 419.952 us; speedup vs baseline: 1.2270x; 1.2270x over previous
//
#include <hip/hip_runtime.h>
#include <hip/hip_fp16.h>
#include <math.h>

#define NJ 24

// SMPL-style kinematic tree; parent index always < child index.
__device__ __constant__ int c_parents[NJ] = {
    -1, 0, 0, 0, 1, 2, 3, 4, 5, 6, 7, 8, 9, 9, 9, 12, 13, 14, 16, 17, 18, 19, 20, 21};

__device__ inline void mat4mul(const float* A, const float* B, float* C) {
#pragma unroll
    for (int r = 0; r < 4; ++r) {
#pragma unroll
        for (int c = 0; c < 4; ++c) {
            C[r * 4 + c] = A[r * 4 + 0] * B[0 * 4 + c] + A[r * 4 + 1] * B[1 * 4 + c] +
                           A[r * 4 + 2] * B[2 * 4 + c] + A[r * 4 + 3] * B[3 * 4 + c];
        }
    }
}

// One block per batch element. Threads 0..23 build local joint transforms,
// thread 0 walks the (tiny, serial) kinematic chain, threads 0..23 compose
// with init_pose and write out. Also computes trans + extra_trans.
__global__ __launch_bounds__(64) void build_A_kernel(
    const float* __restrict__ poses,      // [B, NJ, 3]
    const float* __restrict__ trans,      // [B, 3]
    const float* __restrict__ Js,         // [NJ, 3]
    const float* __restrict__ init_pose,  // [NJ, 4, 4]
    const float* __restrict__ extra_trans,// [1, 3]
    float* __restrict__ A_out,            // [B, NJ, 16]
    float* __restrict__ trans_out,        // [B, 3]
    int B)
{
    __shared__ float Aloc[NJ][16];  // local transforms, composed in place
    int b = blockIdx.x;
    int j = threadIdx.x;

    if (j < NJ) {
        float rx = poses[((size_t)b * NJ + j) * 3 + 0];
        float ry = poses[((size_t)b * NJ + j) * 3 + 1];
        float rz = poses[((size_t)b * NJ + j) * 3 + 2];
        float dot = rx * rx + ry * ry + rz * rz + 1e-12f;
        float angle = sqrtf(dot);
        float inv = 1.0f / angle;
        float ax = rx * inv, ay = ry * inv, az = rz * inv;
        float s = sinf(angle), c = cosf(angle);
        float ic = 1.0f - c;
        // R = c*I + s*K + (1-c)*a a^T  (Rodrigues)
        float R00 = c + ic * ax * ax;
        float R01 = ic * ax * ay - s * az;
        float R02 = ic * ax * az + s * ay;
        float R10 = ic * ax * ay + s * az;
        float R11 = c + ic * ay * ay;
        float R12 = ic * ay * az - s * ax;
        float R20 = ic * ax * az - s * ay;
        float R21 = ic * ay * az + s * ax;
        float R22 = c + ic * az * az;

        int p = c_parents[j];
        float tx = Js[j * 3 + 0], ty = Js[j * 3 + 1], tz = Js[j * 3 + 2];
        if (p >= 0) {
            tx -= Js[p * 3 + 0];
            ty -= Js[p * 3 + 1];
            tz -= Js[p * 3 + 2];
        }
        Aloc[j][0] = R00; Aloc[j][1] = R01; Aloc[j][2]  = R02; Aloc[j][3]  = tx;
        Aloc[j][4] = R10; Aloc[j][5] = R11; Aloc[j][6]  = R12; Aloc[j][7]  = ty;
        Aloc[j][8] = R20; Aloc[j][9] = R21; Aloc[j][10] = R22; Aloc[j][11] = tz;
        Aloc[j][12] = 0.f; Aloc[j][13] = 0.f; Aloc[j][14] = 0.f; Aloc[j][15] = 1.f;
    }
    __syncthreads();

    if (j == 0) {
        // serial chain composition; parents always precede children
        for (int i = 1; i < NJ; ++i) {
            int p = c_parents[i];
            float tmp[16];
            mat4mul(Aloc[p], Aloc[i], tmp);
#pragma unroll
            for (int k = 0; k < 16; ++k) Aloc[i][k] = tmp[k];
        }
    }
    __syncthreads();

    if (j < NJ) {
        float outm[16];
        float ip[16];
#pragma unroll
        for (int k = 0; k < 16; ++k) ip[k] = init_pose[j * 16 + k];
        mat4mul(Aloc[j], ip, outm);
#pragma unroll
        for (int k = 0; k < 16; ++k) A_out[((size_t)b * NJ + j) * 16 + k] = outm[k];
    }
    if (j < 3) {
        trans_out[b * 3 + j] = trans[b * 3 + j] + extra_trans[j];
    }
}

// Transpose [NJ, NVOX] f32 (channel-first) -> [NVOX, NJ] f16 (channel-last).
// One voxel per thread: 24 coalesced dword reads, pack to 12 half2, write
// 48B contiguous per thread (3x dwordx4; L2 merges the 48B-strided parts).
__global__ __launch_bounds__(256) void transpose_h_kernel(
    const float* __restrict__ src, __half* __restrict__ dst, size_t NVOX)
{
    size_t v = (size_t)blockIdx.x * 256 + threadIdx.x;
    if (v >= NVOX) return;

    float vals[NJ];
#pragma unroll
    for (int c = 0; c < NJ; ++c) vals[c] = src[(size_t)c * NVOX + v];

    uint4 o[3];
    __half2* oh = (__half2*)o;
#pragma unroll
    for (int k = 0; k < 12; ++k)
        oh[k] = __floats2half2_rn(vals[2 * k], vals[2 * k + 1]);

    uint4* d = (uint4*)(dst + v * NJ);
    d[0] = o[0];
    d[1] = o[1];
    d[2] = o[2];
}

// Main fused kernel: trilinear sample of 24 fp16 skinning weights (channel-
// last volume) + blend of the 24 joint transforms + point transform.
// Branch-free corners: indices clamped, weights zeroed by in-bounds masks.
__global__ __launch_bounds__(256) void skin_kernel(
    const float* __restrict__ ps,     // [B, N, 3]
    const __half* __restrict__ vol,   // [NVOX, NJ] channel-last fp16
    const float* __restrict__ A,      // [B, NJ, 16]
    const float* __restrict__ transT, // [B, 3]
    const float* __restrict__ bext,   // [3]
    const float* __restrict__ bcen,   // [3]
    float* __restrict__ out,          // [B, N, 3]
    int N, int G)
{
    __shared__ __align__(16) float As[NJ * 16];
    __shared__ float trs[3];
    int b = blockIdx.y;
    int t = threadIdx.x;
    for (int k = t; k < NJ * 16; k += 256) As[k] = A[(size_t)b * NJ * 16 + k];
    if (t < 3) trs[t] = transT[b * 3 + t];
    __syncthreads();

    int i = blockIdx.x * 256 + t;
    if (i >= N) return;

    size_t pix = ((size_t)b * N + i) * 3;
    float px = ps[pix + 0];
    float py = ps[pix + 1];
    float pz = ps[pix + 2];

    float nx = (px - bcen[0]) / bext[0] * 2.0f;
    float ny = (py - bcen[1]) / bext[1] * 2.0f;
    float nz = (pz - bcen[2]) / bext[2] * 2.0f;

    float fG = (float)G;
    float ixf = (nx + 1.0f) * 0.5f * fG - 0.5f;
    float iyf = (ny + 1.0f) * 0.5f * fG - 0.5f;
    float izf = (nz + 1.0f) * 0.5f * fG - 0.5f;

    int x0 = (int)floorf(ixf);
    int y0 = (int)floorf(iyf);
    int z0 = (int)floorf(izf);
    float fx = ixf - (float)x0;
    float fy = iyf - (float)y0;
    float fz = izf - (float)z0;

    // per-axis weights, zeroed when the (unclamped) index is out of bounds
    int x1 = x0 + 1, y1 = y0 + 1, z1 = z0 + 1;
    float wx0 = (1.0f - fx) * ((x0 >= 0 && x0 < G) ? 1.0f : 0.0f);
    float wx1 = fx          * ((x1 >= 0 && x1 < G) ? 1.0f : 0.0f);
    float wy0 = (1.0f - fy) * ((y0 >= 0 && y0 < G) ? 1.0f : 0.0f);
    float wy1 = fy          * ((y1 >= 0 && y1 < G) ? 1.0f : 0.0f);
    float wz0 = (1.0f - fz) * ((z0 >= 0 && z0 < G) ? 1.0f : 0.0f);
    float wz1 = fz          * ((z1 >= 0 && z1 < G) ? 1.0f : 0.0f);

    int x0c = min(max(x0, 0), G - 1), x1c = min(max(x1, 0), G - 1);
    int y0c = min(max(y0, 0), G - 1), y1c = min(max(y1, 0), G - 1);
    int z0c = min(max(z0, 0), G - 1), z1c = min(max(z1, 0), G - 1);

    // 4 row bases (z,y combos) and 2 x offsets -> 8 corner addresses
    size_t rb[4];
    rb[0] = ((size_t)z0c * G + y0c) * (size_t)G;
    rb[1] = ((size_t)z0c * G + y1c) * (size_t)G;
    rb[2] = ((size_t)z1c * G + y0c) * (size_t)G;
    rb[3] = ((size_t)z1c * G + y1c) * (size_t)G;
    float wzy[4] = {wz0 * wy0, wz0 * wy1, wz1 * wy0, wz1 * wy1};

    float w[NJ];
#pragma unroll
    for (int j = 0; j < NJ; ++j) w[j] = 0.0f;

#pragma unroll
    for (int r = 0; r < 4; ++r) {
#pragma unroll
        for (int cx = 0; cx < 2; ++cx) {
            size_t vidx = rb[r] + (cx ? x1c : x0c);
            float cw = wzy[r] * (cx ? wx1 : wx0);
            const uint4* q = (const uint4*)(vol + vidx * NJ);
#pragma unroll
            for (int k = 0; k < 3; ++k) {
                uint4 u = q[k];
                const __half2* h2 = (const __half2*)&u;
#pragma unroll
                for (int m = 0; m < 4; ++m) {
                    float2 f = __half22float2(h2[m]);
                    w[8 * k + 2 * m + 0] += cw * f.x;
                    w[8 * k + 2 * m + 1] += cw * f.y;
                }
            }
        }
    }

    // T = sum_j w[j] * A[b,j]  (rows 0..2 only), then v = T[:3,:3] p + T[:3,3]
    float o[3];
#pragma unroll
    for (int r = 0; r < 3; ++r) {
        float t0 = 0.f, t1 = 0.f, t2 = 0.f, t3 = 0.f;
#pragma unroll
        for (int j = 0; j < NJ; ++j) {
            float4 a4 = *(const float4*)&As[j * 16 + r * 4];
            t0 += w[j] * a4.x;
            t1 += w[j] * a4.y;
            t2 += w[j] * a4.z;
            t3 += w[j] * a4.w;
        }
        o[r] = t0 * px + t1 * py + t2 * pz + t3 + trs[r];
    }

    out[pix + 0] = o[0];
    out[pix + 1] = o[1];
    out[pix + 2] = o[2];
}

extern "C" void kernel_launch(void* const* d_in, const int* in_sizes, int n_in,
                              void* d_out, int out_size, void* d_ws, size_t ws_size,
                              hipStream_t stream) {
    const float* ps        = (const float*)d_in[0];
    const float* poses     = (const float*)d_in[1];
    const float* trans     = (const float*)d_in[2];
    const float* ws        = (const float*)d_in[3];
    const float* Js        = (const float*)d_in[4];
    const float* init_pose = (const float*)d_in[5];
    const float* bext      = (const float*)d_in[6];
    const float* bcen      = (const float*)d_in[7];
    const float* etr       = (const float*)d_in[8];
    float* out = (float*)d_out;

    int B = in_sizes[2] / 3;
    int N = in_sizes[0] / (3 * B);
    long long wsz = in_sizes[3];
    int G = (int)(cbrt((double)(wsz / NJ)) + 0.5);
    size_t NVOX = (size_t)G * G * G;

    // Workspace layout: [A: B*NJ*16 f32][trans: B*3 f32][pad][vol_t: NVOX*NJ f16]
    size_t a_floats = (size_t)B * NJ * 16;
    size_t t_floats = (size_t)B * 3;
    size_t vol_off_f = (a_floats + t_floats + 63) & ~(size_t)63;  // 256B align

    float* A_buf = (float*)d_ws;
    float* tr_buf = A_buf + a_floats;
    __half* vol_t = (__half*)((float*)d_ws + vol_off_f);

    build_A_kernel<<<B, 64, 0, stream>>>(poses, trans, Js, init_pose, etr,
                                         A_buf, tr_buf, B);

    int nb = (int)((NVOX + 255) / 256);
    transpose_h_kernel<<<nb, 256, 0, stream>>>(ws, vol_t, NVOX);

    dim3 grid((unsigned)((N + 255) / 256), (unsigned)B);
    skin_kernel<<<grid, 256, 0, stream>>>(ps, vol_t, A_buf, tr_buf,
                                          bext, bcen, out, N, G);
}

// Round 4
// 419.531 us; speedup vs baseline: 1.2282x; 1.0010x over previous
//
#include <hip/hip_runtime.h>
#include <hip/hip_fp16.h>
#include <math.h>

#define NJ 24

// SMPL-style kinematic tree; parent index always < child index.
__device__ __constant__ int c_parents[NJ] = {
    -1, 0, 0, 0, 1, 2, 3, 4, 5, 6, 7, 8, 9, 9, 9, 12, 13, 14, 16, 17, 18, 19, 20, 21};

__device__ inline void mat4mul(const float* A, const float* B, float* C) {
#pragma unroll
    for (int r = 0; r < 4; ++r) {
#pragma unroll
        for (int c = 0; c < 4; ++c) {
            C[r * 4 + c] = A[r * 4 + 0] * B[0 * 4 + c] + A[r * 4 + 1] * B[1 * 4 + c] +
                           A[r * 4 + 2] * B[2 * 4 + c] + A[r * 4 + 3] * B[3 * 4 + c];
        }
    }
}

// One block per batch element. Threads 0..23 build local joint transforms,
// thread 0 walks the (tiny, serial) kinematic chain, threads 0..23 compose
// with init_pose and write out. Also computes trans + extra_trans.
__global__ __launch_bounds__(64) void build_A_kernel(
    const float* __restrict__ poses,      // [B, NJ, 3]
    const float* __restrict__ trans,      // [B, 3]
    const float* __restrict__ Js,         // [NJ, 3]
    const float* __restrict__ init_pose,  // [NJ, 4, 4]
    const float* __restrict__ extra_trans,// [1, 3]
    float* __restrict__ A_out,            // [B, NJ, 16]
    float* __restrict__ trans_out,        // [B, 3]
    int B)
{
    __shared__ float Aloc[NJ][16];  // local transforms, composed in place
    int b = blockIdx.x;
    int j = threadIdx.x;

    if (j < NJ) {
        float rx = poses[((size_t)b * NJ + j) * 3 + 0];
        float ry = poses[((size_t)b * NJ + j) * 3 + 1];
        float rz = poses[((size_t)b * NJ + j) * 3 + 2];
        float dot = rx * rx + ry * ry + rz * rz + 1e-12f;
        float angle = sqrtf(dot);
        float inv = 1.0f / angle;
        float ax = rx * inv, ay = ry * inv, az = rz * inv;
        float s = sinf(angle), c = cosf(angle);
        float ic = 1.0f - c;
        // R = c*I + s*K + (1-c)*a a^T  (Rodrigues)
        float R00 = c + ic * ax * ax;
        float R01 = ic * ax * ay - s * az;
        float R02 = ic * ax * az + s * ay;
        float R10 = ic * ax * ay + s * az;
        float R11 = c + ic * ay * ay;
        float R12 = ic * ay * az - s * ax;
        float R20 = ic * ax * az - s * ay;
        float R21 = ic * ay * az + s * ax;
        float R22 = c + ic * az * az;

        int p = c_parents[j];
        float tx = Js[j * 3 + 0], ty = Js[j * 3 + 1], tz = Js[j * 3 + 2];
        if (p >= 0) {
            tx -= Js[p * 3 + 0];
            ty -= Js[p * 3 + 1];
            tz -= Js[p * 3 + 2];
        }
        Aloc[j][0] = R00; Aloc[j][1] = R01; Aloc[j][2]  = R02; Aloc[j][3]  = tx;
        Aloc[j][4] = R10; Aloc[j][5] = R11; Aloc[j][6]  = R12; Aloc[j][7]  = ty;
        Aloc[j][8] = R20; Aloc[j][9] = R21; Aloc[j][10] = R22; Aloc[j][11] = tz;
        Aloc[j][12] = 0.f; Aloc[j][13] = 0.f; Aloc[j][14] = 0.f; Aloc[j][15] = 1.f;
    }
    __syncthreads();

    if (j == 0) {
        // serial chain composition; parents always precede children
        for (int i = 1; i < NJ; ++i) {
            int p = c_parents[i];
            float tmp[16];
            mat4mul(Aloc[p], Aloc[i], tmp);
#pragma unroll
            for (int k = 0; k < 16; ++k) Aloc[i][k] = tmp[k];
        }
    }
    __syncthreads();

    if (j < NJ) {
        float outm[16];
        float ip[16];
#pragma unroll
        for (int k = 0; k < 16; ++k) ip[k] = init_pose[j * 16 + k];
        mat4mul(Aloc[j], ip, outm);
#pragma unroll
        for (int k = 0; k < 16; ++k) A_out[((size_t)b * NJ + j) * 16 + k] = outm[k];
    }
    if (j < 3) {
        trans_out[b * 3 + j] = trans[b * 3 + j] + extra_trans[j];
    }
}

// Transpose [NJ, NVOX] f32 (channel-first) -> [NVOX, NJ] f16 (channel-last),
// LDS-staged so BOTH sides are fully coalesced.
//   Phase 1: channel-major dword reads (64 lanes x 4B contiguous per instr),
//            pack half2, store to LDS tile [512][13 dwords] (12 used + 1 pad;
//            13 coprime 32 -> phase-1 writes are the free 2-way bank pattern).
//   Phase 2: stream the 512*48B = 24KB tile out as dwordx4, 64 lanes x 16B =
//            1KB contiguous per wave instruction.
#define T_TPB 256
#define T_VPT 2
#define T_TILE (T_TPB * T_VPT)  // 512 voxels per block
#define T_ROWD 13               // LDS dwords per voxel row

__global__ __launch_bounds__(T_TPB) void transpose_h_kernel(
    const float* __restrict__ src, __half* __restrict__ dst, size_t NVOX)
{
    __shared__ unsigned lds[T_TILE * T_ROWD];  // 26.6 KB
    size_t V0 = (size_t)blockIdx.x * T_TILE;
    int t = threadIdx.x;

#pragma unroll
    for (int s = 0; s < T_VPT; ++s) {
        int v = t + s * T_TPB;
        size_t gv = V0 + v;
        size_t gsafe = (gv < NVOX) ? gv : (NVOX - 1);
#pragma unroll
        for (int c4 = 0; c4 < 12; ++c4) {
            float f0 = src[(size_t)(2 * c4 + 0) * NVOX + gsafe];
            float f1 = src[(size_t)(2 * c4 + 1) * NVOX + gsafe];
            __half2 h = __floats2half2_rn(f0, f1);
            lds[v * T_ROWD + c4] = *(unsigned*)&h;
        }
    }
    __syncthreads();

#pragma unroll
    for (int k = 0; k < 6; ++k) {
        int s = t + k * T_TPB;      // 0..1535 : dword4 index within tile
        int v = s / 3;
        int off = (s % 3) * 4;      // dword offset within the voxel row
        uint4 u;
        u.x = lds[v * T_ROWD + off + 0];
        u.y = lds[v * T_ROWD + off + 1];
        u.z = lds[v * T_ROWD + off + 2];
        u.w = lds[v * T_ROWD + off + 3];
        if (V0 + (size_t)v < NVOX) {
            *(uint4*)((char*)dst + V0 * (NJ * 2) + (size_t)s * 16) = u;
        }
    }
}

// Main fused kernel: trilinear sample of 24 fp16 skinning weights (channel-
// last volume) + blend of the 24 joint transforms + point transform.
// Branch-free corners: indices clamped, weights zeroed by in-bounds masks.
__global__ __launch_bounds__(256) void skin_kernel(
    const float* __restrict__ ps,     // [B, N, 3]
    const __half* __restrict__ vol,   // [NVOX, NJ] channel-last fp16
    const float* __restrict__ A,      // [B, NJ, 16]
    const float* __restrict__ transT, // [B, 3]
    const float* __restrict__ bext,   // [3]
    const float* __restrict__ bcen,   // [3]
    float* __restrict__ out,          // [B, N, 3]
    int N, int G)
{
    __shared__ __align__(16) float As[NJ * 16];
    __shared__ float trs[3];
    int b = blockIdx.y;
    int t = threadIdx.x;
    for (int k = t; k < NJ * 16; k += 256) As[k] = A[(size_t)b * NJ * 16 + k];
    if (t < 3) trs[t] = transT[b * 3 + t];
    __syncthreads();

    int i = blockIdx.x * 256 + t;
    if (i >= N) return;

    size_t pix = ((size_t)b * N + i) * 3;
    float px = ps[pix + 0];
    float py = ps[pix + 1];
    float pz = ps[pix + 2];

    float nx = (px - bcen[0]) / bext[0] * 2.0f;
    float ny = (py - bcen[1]) / bext[1] * 2.0f;
    float nz = (pz - bcen[2]) / bext[2] * 2.0f;

    float fG = (float)G;
    float ixf = (nx + 1.0f) * 0.5f * fG - 0.5f;
    float iyf = (ny + 1.0f) * 0.5f * fG - 0.5f;
    float izf = (nz + 1.0f) * 0.5f * fG - 0.5f;

    int x0 = (int)floorf(ixf);
    int y0 = (int)floorf(iyf);
    int z0 = (int)floorf(izf);
    float fx = ixf - (float)x0;
    float fy = iyf - (float)y0;
    float fz = izf - (float)z0;

    // per-axis weights, zeroed when the (unclamped) index is out of bounds
    int x1 = x0 + 1, y1 = y0 + 1, z1 = z0 + 1;
    float wx0 = (1.0f - fx) * ((x0 >= 0 && x0 < G) ? 1.0f : 0.0f);
    float wx1 = fx          * ((x1 >= 0 && x1 < G) ? 1.0f : 0.0f);
    float wy0 = (1.0f - fy) * ((y0 >= 0 && y0 < G) ? 1.0f : 0.0f);
    float wy1 = fy          * ((y1 >= 0 && y1 < G) ? 1.0f : 0.0f);
    float wz0 = (1.0f - fz) * ((z0 >= 0 && z0 < G) ? 1.0f : 0.0f);
    float wz1 = fz          * ((z1 >= 0 && z1 < G) ? 1.0f : 0.0f);

    int x0c = min(max(x0, 0), G - 1), x1c = min(max(x1, 0), G - 1);
    int y0c = min(max(y0, 0), G - 1), y1c = min(max(y1, 0), G - 1);
    int z0c = min(max(z0, 0), G - 1), z1c = min(max(z1, 0), G - 1);

    // 4 row bases (z,y combos) and 2 x offsets -> 8 corner addresses
    size_t rb[4];
    rb[0] = ((size_t)z0c * G + y0c) * (size_t)G;
    rb[1] = ((size_t)z0c * G + y1c) * (size_t)G;
    rb[2] = ((size_t)z1c * G + y0c) * (size_t)G;
    rb[3] = ((size_t)z1c * G + y1c) * (size_t)G;
    float wzy[4] = {wz0 * wy0, wz0 * wy1, wz1 * wy0, wz1 * wy1};

    float w[NJ];
#pragma unroll
    for (int j = 0; j < NJ; ++j) w[j] = 0.0f;

#pragma unroll
    for (int r = 0; r < 4; ++r) {
#pragma unroll
        for (int cx = 0; cx < 2; ++cx) {
            size_t vidx = rb[r] + (cx ? x1c : x0c);
            float cw = wzy[r] * (cx ? wx1 : wx0);
            const uint4* q = (const uint4*)(vol + vidx * NJ);
#pragma unroll
            for (int k = 0; k < 3; ++k) {
                uint4 u = q[k];
                const __half2* h2 = (const __half2*)&u;
#pragma unroll
                for (int m = 0; m < 4; ++m) {
                    float2 f = __half22float2(h2[m]);
                    w[8 * k + 2 * m + 0] += cw * f.x;
                    w[8 * k + 2 * m + 1] += cw * f.y;
                }
            }
        }
    }

    // T = sum_j w[j] * A[b,j]  (rows 0..2 only), then v = T[:3,:3] p + T[:3,3]
    float o[3];
#pragma unroll
    for (int r = 0; r < 3; ++r) {
        float t0 = 0.f, t1 = 0.f, t2 = 0.f, t3 = 0.f;
#pragma unroll
        for (int j = 0; j < NJ; ++j) {
            float4 a4 = *(const float4*)&As[j * 16 + r * 4];
            t0 += w[j] * a4.x;
            t1 += w[j] * a4.y;
            t2 += w[j] * a4.z;
            t3 += w[j] * a4.w;
        }
        o[r] = t0 * px + t1 * py + t2 * pz + t3 + trs[r];
    }

    out[pix + 0] = o[0];
    out[pix + 1] = o[1];
    out[pix + 2] = o[2];
}

extern "C" void kernel_launch(void* const* d_in, const int* in_sizes, int n_in,
                              void* d_out, int out_size, void* d_ws, size_t ws_size,
                              hipStream_t stream) {
    const float* ps        = (const float*)d_in[0];
    const float* poses     = (const float*)d_in[1];
    const float* trans     = (const float*)d_in[2];
    const float* ws        = (const float*)d_in[3];
    const float* Js        = (const float*)d_in[4];
    const float* init_pose = (const float*)d_in[5];
    const float* bext      = (const float*)d_in[6];
    const float* bcen      = (const float*)d_in[7];
    const float* etr       = (const float*)d_in[8];
    float* out = (float*)d_out;

    int B = in_sizes[2] / 3;
    int N = in_sizes[0] / (3 * B);
    long long wsz = in_sizes[3];
    int G = (int)(cbrt((double)(wsz / NJ)) + 0.5);
    size_t NVOX = (size_t)G * G * G;

    // Workspace layout: [A: B*NJ*16 f32][trans: B*3 f32][pad][vol_t: NVOX*NJ f16]
    size_t a_floats = (size_t)B * NJ * 16;
    size_t t_floats = (size_t)B * 3;
    size_t vol_off_f = (a_floats + t_floats + 63) & ~(size_t)63;  // 256B align

    float* A_buf = (float*)d_ws;
    float* tr_buf = A_buf + a_floats;
    __half* vol_t = (__half*)((float*)d_ws + vol_off_f);

    build_A_kernel<<<B, 64, 0, stream>>>(poses, trans, Js, init_pose, etr,
                                         A_buf, tr_buf, B);

    int nb = (int)((NVOX + T_TILE - 1) / T_TILE);
    transpose_h_kernel<<<nb, T_TPB, 0, stream>>>(ws, vol_t, NVOX);

    dim3 grid((unsigned)((N + 255) / 256), (unsigned)B);
    skin_kernel<<<grid, 256, 0, stream>>>(ps, vol_t, A_buf, tr_buf,
                                          bext, bcen, out, N, G);
}